// Round 1
// baseline (749.588 us; speedup 1.0000x reference)
//
#include <hip/hip_runtime.h>

// GAT 2-layer, N=100000 nodes, E=1.6M edges, dims 128->64->64, all fp32.
// Strategy:
//   - s[i] = a[i]·we collapses edge-logit GEMV to per-node scalar (We is [1,64]).
//   - tanh-bounded logits => skip segment_max (exp(e)/sum(exp(e)) is exact same ratio).
//   - CSR by src built in workspace each call (atomic histogram + 2-level scan + scatter).
//   - aggregation kernel: one wave per node, lane = output dim; fuses softmax
//     denominator, weighted sum of v[dst], and std(ddof=1) row normalization.

#define WS_ALIGN 256

__device__ __forceinline__ float wave_sum(float x) {
#pragma unroll
  for (int m = 32; m > 0; m >>= 1) x += __shfl_xor(x, m, 64);
  return x;
}

__device__ __forceinline__ float fast_tanh(float x) {
  // tanh(x) = (e^{2x}-1)/(e^{2x}+1); clamp keeps e finite (tanh(±15)==±1 in fp32)
  x = fminf(15.f, fmaxf(-15.f, x));
  float e = __expf(2.f * x);
  return (e - 1.f) * __builtin_amdgcn_rcpf(e + 1.f);
}

__global__ void k_zero(int* __restrict__ p, int n) {
  int i = blockIdx.x * 256 + threadIdx.x;
  if (i < n) p[i] = 0;
}

__global__ void k_deg(const int* __restrict__ src, int* __restrict__ deg, int E) {
  int e = blockIdx.x * 256 + threadIdx.x;
  if (e < E) atomicAdd(&deg[src[e]], 1);
}

// chunk = 1024 elements per block (256 threads x 4)
__global__ void k_scan_part(const int* __restrict__ deg, int* __restrict__ pre,
                            int* __restrict__ bsum, int n) {
  __shared__ int sdat[256];
  int t = threadIdx.x;
  int base = blockIdx.x * 1024 + t * 4;
  int v[4];
#pragma unroll
  for (int j = 0; j < 4; j++) {
    int i = base + j;
    v[j] = (i < n) ? deg[i] : 0;
  }
  int tsum = v[0] + v[1] + v[2] + v[3];
  sdat[t] = tsum;
  __syncthreads();
  for (int off = 1; off < 256; off <<= 1) {
    int add = (t >= off) ? sdat[t - off] : 0;
    __syncthreads();
    sdat[t] += add;
    __syncthreads();
  }
  int ex = sdat[t] - tsum;  // exclusive within block
#pragma unroll
  for (int j = 0; j < 4; j++) {
    int i = base + j;
    if (i < n) pre[i] = ex;
    ex += v[j];
  }
  if (t == 255) bsum[blockIdx.x] = sdat[255];
}

// single block of 128 threads scans <=128 block sums (N=100k -> 98 blocks)
__global__ void k_scan_top(int* __restrict__ bsum, int nb) {
  __shared__ int sdat[128];
  int t = threadIdx.x;
  int v = (t < nb) ? bsum[t] : 0;
  sdat[t] = v;
  __syncthreads();
  for (int off = 1; off < 128; off <<= 1) {
    int add = (t >= off) ? sdat[t - off] : 0;
    __syncthreads();
    sdat[t] += add;
    __syncthreads();
  }
  if (t < nb) bsum[t] = sdat[t] - v;  // exclusive
}

__global__ void k_scan_add(const int* __restrict__ pre, const int* __restrict__ bsum,
                           int* __restrict__ rowptr, int* __restrict__ cursor, int n, int E) {
  int base = blockIdx.x * 1024 + threadIdx.x * 4;
  int off = bsum[blockIdx.x];
#pragma unroll
  for (int j = 0; j < 4; j++) {
    int i = base + j;
    if (i < n) {
      int r = pre[i] + off;
      rowptr[i] = r;
      cursor[i] = r;
    }
  }
  if (blockIdx.x == 0 && threadIdx.x == 0) rowptr[n] = E;
}

__global__ void k_scatter(const int* __restrict__ src, const int* __restrict__ dst,
                          int* __restrict__ cursor, int* __restrict__ col,
                          int* __restrict__ srcp, int E) {
  int e = blockIdx.x * 256 + threadIdx.x;
  if (e < E) {
    int s = src[e];
    int p = atomicAdd(&cursor[s], 1);
    col[p] = dst[e];
    srcp[p] = s;
  }
}

// Fused per-node kernel: v = tanh(x@Wv^T+bv) stored [N,64]; s = tanh(x@Wa^T+ba)·we
// stored [N]. 4 waves/block, 8 nodes/wave (lane = output dim).
// W staged in LDS as [k/4][64 dims][4] float4 => contiguous conflict-free ds_read_b128.
// x read via wave-uniform addresses (readfirstlane) -> scalar-load friendly.
// NOTE: requires n % 32 == 0 (true: 100000 = 3125*32).
template <int K>
__global__ __launch_bounds__(256, 2) void k_node(
    const float* __restrict__ x, const float* __restrict__ Wa, const float* __restrict__ ba,
    const float* __restrict__ we, const float* __restrict__ Wv, const float* __restrict__ bv,
    float* __restrict__ v_out, float* __restrict__ s_out, int n) {
  constexpr int KB = K / 4;
  __shared__ float4 sWa[64 * KB];
  __shared__ float4 sWv[64 * KB];
  const float4* Wa4 = (const float4*)Wa;
  const float4* Wv4 = (const float4*)Wv;
  for (int f = threadIdx.x; f < 64 * KB; f += 256) {
    int o = f / KB, kb = f - o * KB;
    sWa[kb * 64 + o] = Wa4[f];
    sWv[kb * 64 + o] = Wv4[f];
  }
  __syncthreads();

  int l = threadIdx.x & 63;
  int w = __builtin_amdgcn_readfirstlane(threadIdx.x >> 6);
  int node0 = blockIdx.x * 32 + w * 8;
  if (node0 >= n) return;
  const float4* xr = (const float4*)x + (size_t)node0 * KB;

  float acc_a[8], acc_v[8];
#pragma unroll
  for (int i = 0; i < 8; i++) { acc_a[i] = 0.f; acc_v[i] = 0.f; }

  for (int kb = 0; kb < KB; kb++) {
    float4 wa = sWa[kb * 64 + l];
    float4 wv = sWv[kb * 64 + l];
#pragma unroll
    for (int i = 0; i < 8; i++) {
      float4 xv = xr[(size_t)i * KB + kb];
      acc_a[i] = fmaf(xv.x, wa.x, fmaf(xv.y, wa.y, fmaf(xv.z, wa.z, fmaf(xv.w, wa.w, acc_a[i]))));
      acc_v[i] = fmaf(xv.x, wv.x, fmaf(xv.y, wv.y, fmaf(xv.z, wv.z, fmaf(xv.w, wv.w, acc_v[i]))));
    }
  }

  float bal = ba[l], bvl = bv[l], wel = we[l];
#pragma unroll
  for (int i = 0; i < 8; i++) {
    int node = node0 + i;
    float a = fast_tanh(acc_a[i] + bal);
    float vv = fast_tanh(acc_v[i] + bvl);
    v_out[(size_t)node * 64 + l] = vv;
    float sv = wave_sum(a * wel);
    if (l == 0) s_out[node] = sv;
  }
}

// per-edge weight, computed once per edge (not 64x redundantly in the wave kernel)
__global__ void k_edgew(const int* __restrict__ srcp, const int* __restrict__ col,
                        const float* __restrict__ s, const float* __restrict__ be_p,
                        float* __restrict__ wq, int E) {
  int e = blockIdx.x * 256 + threadIdx.x;
  if (e < E) {
    float xx = s[srcp[e]] + s[col[e]] + be_p[0];
    wq[e] = __expf(fast_tanh(xx));
  }
}

// one wave per node; lane = output dim; fused softmax-normalize + aggregate + std(ddof=1)
__global__ __launch_bounds__(256) void k_aggr(const int* __restrict__ rowptr,
                                              const int* __restrict__ col,
                                              const float* __restrict__ wq,
                                              const float* __restrict__ v,
                                              float* __restrict__ out, int n) {
  int gw = (int)((blockIdx.x * 256 + threadIdx.x) >> 6);
  int l = threadIdx.x & 63;
  if (gw >= n) return;
  int e0 = rowptr[gw], e1 = rowptr[gw + 1];
  float acc = 0.f, denom = 0.f;
  for (int e = e0; e < e1; e++) {
    float wgt = wq[e];
    int d = col[e];
    denom += wgt;
    acc = fmaf(wgt, v[(size_t)d * 64 + l], acc);
  }
  float o = acc / denom;
  float sum = wave_sum(o);
  float sumsq = wave_sum(o * o);
  float var = (sumsq - sum * sum * (1.0f / 64.f)) * (1.0f / 63.f);
  out[(size_t)gw * 64 + l] = o / sqrtf(var);
}

extern "C" void kernel_launch(void* const* d_in, const int* in_sizes, int n_in,
                              void* d_out, int out_size, void* d_ws, size_t ws_size,
                              hipStream_t stream) {
  const float* h = (const float*)d_in[0];
  const int* ei = (const int*)d_in[1];
  const float* W11 = (const float*)d_in[2];
  const float* b11 = (const float*)d_in[3];
  const float* W12 = (const float*)d_in[4];  // [1,64] -> 64-vec
  const float* b12 = (const float*)d_in[5];
  const float* W13 = (const float*)d_in[6];
  const float* b13 = (const float*)d_in[7];
  const float* W21 = (const float*)d_in[8];
  const float* b21 = (const float*)d_in[9];
  const float* W22 = (const float*)d_in[10];
  const float* b22 = (const float*)d_in[11];
  const float* W23 = (const float*)d_in[12];
  const float* b23 = (const float*)d_in[13];

  const int N = in_sizes[0] / 128;  // 100000
  const int E = in_sizes[1] / 2;    // 1600000
  const int* src = ei;
  const int* dst = ei + E;

  // workspace carve-up (~73 MB total)
  char* p = (char*)d_ws;
  auto alloc = [&](size_t bytes) -> void* {
    void* r = (void*)p;
    p += (bytes + WS_ALIGN - 1) / WS_ALIGN * WS_ALIGN;
    return r;
  };
  int* deg = (int*)alloc((size_t)N * 4);
  int* pre = (int*)alloc((size_t)N * 4);
  int* bsum = (int*)alloc(512);
  int* rowptr = (int*)alloc((size_t)(N + 1) * 4);
  int* cursor = (int*)alloc((size_t)N * 4);
  int* col = (int*)alloc((size_t)E * 4);
  int* srcp = (int*)alloc((size_t)E * 4);
  float* wq = (float*)alloc((size_t)E * 4);
  float* sbuf = (float*)alloc((size_t)N * 4);
  float* vbuf = (float*)alloc((size_t)N * 64 * 4);
  float* out1 = (float*)alloc((size_t)N * 64 * 4);

  const int SB = (N + 1023) / 1024;  // 98 (must be <= 128 for k_scan_top)

  // ---- CSR build (reused by both layers) ----
  k_zero<<<(N + 255) / 256, 256, 0, stream>>>(deg, N);
  k_deg<<<(E + 255) / 256, 256, 0, stream>>>(src, deg, E);
  k_scan_part<<<SB, 256, 0, stream>>>(deg, pre, bsum, N);
  k_scan_top<<<1, 128, 0, stream>>>(bsum, SB);
  k_scan_add<<<SB, 256, 0, stream>>>(pre, bsum, rowptr, cursor, N, E);
  k_scatter<<<(E + 255) / 256, 256, 0, stream>>>(src, dst, cursor, col, srcp, E);

  // ---- layer 1 (K=128) ----
  k_node<128><<<(N + 31) / 32, 256, 0, stream>>>(h, W11, b11, W12, W13, b13, vbuf, sbuf, N);
  k_edgew<<<(E + 255) / 256, 256, 0, stream>>>(srcp, col, sbuf, b12, wq, E);
  k_aggr<<<(N + 3) / 4, 256, 0, stream>>>(rowptr, col, wq, vbuf, out1, N);

  // ---- layer 2 (K=64) ----
  k_node<64><<<(N + 31) / 32, 256, 0, stream>>>(out1, W21, b21, W22, W23, b23, vbuf, sbuf, N);
  k_edgew<<<(E + 255) / 256, 256, 0, stream>>>(srcp, col, sbuf, b22, wq, E);
  k_aggr<<<(N + 3) / 4, 256, 0, stream>>>(rowptr, col, wq, vbuf, (float*)d_out, N);
}

// Round 2
// 569.666 us; speedup vs baseline: 1.3158x; 1.3158x over previous
//
#include <hip/hip_runtime.h>

// GAT 2-layer, N=100000 nodes, E=1.6M edges, dims 128->64->64, all fp32.
// Strategy:
//   - s[i] = a[i]·we collapses edge-logit GEMV to per-node scalar (We is [1,64]).
//   - tanh-bounded logits => skip segment_max (exp(e)/sum(exp(e)) is exact same ratio).
//   - CSR by src built in workspace each call (atomic histogram + 2-level scan + scatter).
//   - aggregation kernel v2: one wave per node, lane = output dim. Edge weights
//     computed IN-kernel (k_edgew fused away): cols + s[col] gathered lane-parallel
//     (one coalesced load instead of 16 serialized broadcasts), weights broadcast by
//     readlane, v-row gathers unrolled 8-deep for MLP. Fuses softmax denom, weighted
//     aggregate, and std(ddof=1) row normalization.

#define WS_ALIGN 256

__device__ __forceinline__ float wave_sum(float x) {
#pragma unroll
  for (int m = 32; m > 0; m >>= 1) x += __shfl_xor(x, m, 64);
  return x;
}

__device__ __forceinline__ float fast_tanh(float x) {
  // tanh(x) = (e^{2x}-1)/(e^{2x}+1); clamp keeps e finite (tanh(±15)==±1 in fp32)
  x = fminf(15.f, fmaxf(-15.f, x));
  float e = __expf(2.f * x);
  return (e - 1.f) * __builtin_amdgcn_rcpf(e + 1.f);
}

__global__ void k_zero(int* __restrict__ p, int n) {
  int i = blockIdx.x * 256 + threadIdx.x;
  if (i < n) p[i] = 0;
}

__global__ void k_deg(const int* __restrict__ src, int* __restrict__ deg, int E) {
  int e = blockIdx.x * 256 + threadIdx.x;
  if (e < E) atomicAdd(&deg[src[e]], 1);
}

// chunk = 1024 elements per block (256 threads x 4)
__global__ void k_scan_part(const int* __restrict__ deg, int* __restrict__ pre,
                            int* __restrict__ bsum, int n) {
  __shared__ int sdat[256];
  int t = threadIdx.x;
  int base = blockIdx.x * 1024 + t * 4;
  int v[4];
#pragma unroll
  for (int j = 0; j < 4; j++) {
    int i = base + j;
    v[j] = (i < n) ? deg[i] : 0;
  }
  int tsum = v[0] + v[1] + v[2] + v[3];
  sdat[t] = tsum;
  __syncthreads();
  for (int off = 1; off < 256; off <<= 1) {
    int add = (t >= off) ? sdat[t - off] : 0;
    __syncthreads();
    sdat[t] += add;
    __syncthreads();
  }
  int ex = sdat[t] - tsum;  // exclusive within block
#pragma unroll
  for (int j = 0; j < 4; j++) {
    int i = base + j;
    if (i < n) pre[i] = ex;
    ex += v[j];
  }
  if (t == 255) bsum[blockIdx.x] = sdat[255];
}

// single block of 128 threads scans <=128 block sums (N=100k -> 98 blocks)
__global__ void k_scan_top(int* __restrict__ bsum, int nb) {
  __shared__ int sdat[128];
  int t = threadIdx.x;
  int v = (t < nb) ? bsum[t] : 0;
  sdat[t] = v;
  __syncthreads();
  for (int off = 1; off < 128; off <<= 1) {
    int add = (t >= off) ? sdat[t - off] : 0;
    __syncthreads();
    sdat[t] += add;
    __syncthreads();
  }
  if (t < nb) bsum[t] = sdat[t] - v;  // exclusive
}

__global__ void k_scan_add(const int* __restrict__ pre, const int* __restrict__ bsum,
                           int* __restrict__ rowptr, int* __restrict__ cursor, int n, int E) {
  int base = blockIdx.x * 1024 + threadIdx.x * 4;
  int off = bsum[blockIdx.x];
#pragma unroll
  for (int j = 0; j < 4; j++) {
    int i = base + j;
    if (i < n) {
      int r = pre[i] + off;
      rowptr[i] = r;
      cursor[i] = r;
    }
  }
  if (blockIdx.x == 0 && threadIdx.x == 0) rowptr[n] = E;
}

__global__ void k_scatter(const int* __restrict__ src, const int* __restrict__ dst,
                          int* __restrict__ cursor, int* __restrict__ col, int E) {
  int e = blockIdx.x * 256 + threadIdx.x;
  if (e < E) {
    int s = src[e];
    int p = atomicAdd(&cursor[s], 1);
    col[p] = dst[e];
  }
}

// Fused per-node kernel: v = tanh(x@Wv^T+bv) stored [N,64]; s = tanh(x@Wa^T+ba)·we
// stored [N]. 4 waves/block, 8 nodes/wave (lane = output dim).
// W staged in LDS as [k/4][64 dims][4] float4 => contiguous conflict-free ds_read_b128.
// NOTE: requires n % 32 == 0 (true: 100000 = 3125*32).
template <int K>
__global__ __launch_bounds__(256, 2) void k_node(
    const float* __restrict__ x, const float* __restrict__ Wa, const float* __restrict__ ba,
    const float* __restrict__ we, const float* __restrict__ Wv, const float* __restrict__ bv,
    float* __restrict__ v_out, float* __restrict__ s_out, int n) {
  constexpr int KB = K / 4;
  __shared__ float4 sWa[64 * KB];
  __shared__ float4 sWv[64 * KB];
  const float4* Wa4 = (const float4*)Wa;
  const float4* Wv4 = (const float4*)Wv;
  for (int f = threadIdx.x; f < 64 * KB; f += 256) {
    int o = f / KB, kb = f - o * KB;
    sWa[kb * 64 + o] = Wa4[f];
    sWv[kb * 64 + o] = Wv4[f];
  }
  __syncthreads();

  int l = threadIdx.x & 63;
  int w = __builtin_amdgcn_readfirstlane(threadIdx.x >> 6);
  int node0 = blockIdx.x * 32 + w * 8;
  if (node0 >= n) return;
  const float4* xr = (const float4*)x + (size_t)node0 * KB;

  float acc_a[8], acc_v[8];
#pragma unroll
  for (int i = 0; i < 8; i++) { acc_a[i] = 0.f; acc_v[i] = 0.f; }

  for (int kb = 0; kb < KB; kb++) {
    float4 wa = sWa[kb * 64 + l];
    float4 wv = sWv[kb * 64 + l];
#pragma unroll
    for (int i = 0; i < 8; i++) {
      float4 xv = xr[(size_t)i * KB + kb];
      acc_a[i] = fmaf(xv.x, wa.x, fmaf(xv.y, wa.y, fmaf(xv.z, wa.z, fmaf(xv.w, wa.w, acc_a[i]))));
      acc_v[i] = fmaf(xv.x, wv.x, fmaf(xv.y, wv.y, fmaf(xv.z, wv.z, fmaf(xv.w, wv.w, acc_v[i]))));
    }
  }

  float bal = ba[l], bvl = bv[l], wel = we[l];
#pragma unroll
  for (int i = 0; i < 8; i++) {
    int node = node0 + i;
    float a = fast_tanh(acc_a[i] + bal);
    float vv = fast_tanh(acc_v[i] + bvl);
    v_out[(size_t)node * 64 + l] = vv;
    float sv = wave_sum(a * wel);
    if (l == 0) s_out[node] = sv;
  }
}

// one wave per node; lane = output dim. Edge weights computed in-kernel:
// lane-parallel col/s gather (coalesced), readlane broadcast, v gathers 8-deep.
__global__ __launch_bounds__(256) void k_aggr(const int* __restrict__ rowptr,
                                              const int* __restrict__ col,
                                              const float* __restrict__ s,
                                              const float* __restrict__ be_p,
                                              const float* __restrict__ v,
                                              float* __restrict__ out, int n) {
  int gw = (int)((blockIdx.x * 256 + threadIdx.x) >> 6);
  int l = threadIdx.x & 63;
  if (gw >= n) return;
  int e0 = rowptr[gw], e1 = rowptr[gw + 1];
  float srow = s[gw];
  float be = be_p[0];
  float acc = 0.f, denom = 0.f;

  for (int base = e0; base < e1; base += 64) {
    int m = e1 - base;
    if (m > 64) m = 64;
    // lane-parallel: one coalesced col load + one s gather + weight for edge base+l
    int c = 0;
    float w = 0.f;
    if (l < m) {
      c = col[base + l];
      w = __expf(fast_tanh(srow + s[c] + be));
    }
    denom += wave_sum(w);

    int j = 0;
    for (; j + 8 <= m; j += 8) {
      int c0 = __shfl(c, j), c1 = __shfl(c, j + 1), c2 = __shfl(c, j + 2), c3 = __shfl(c, j + 3);
      int c4 = __shfl(c, j + 4), c5 = __shfl(c, j + 5), c6 = __shfl(c, j + 6), c7 = __shfl(c, j + 7);
      float w0 = __shfl(w, j), w1 = __shfl(w, j + 1), w2 = __shfl(w, j + 2), w3 = __shfl(w, j + 3);
      float w4 = __shfl(w, j + 4), w5 = __shfl(w, j + 5), w6 = __shfl(w, j + 6), w7 = __shfl(w, j + 7);
      float v0 = v[(size_t)c0 * 64 + l];
      float v1 = v[(size_t)c1 * 64 + l];
      float v2 = v[(size_t)c2 * 64 + l];
      float v3 = v[(size_t)c3 * 64 + l];
      float v4 = v[(size_t)c4 * 64 + l];
      float v5 = v[(size_t)c5 * 64 + l];
      float v6 = v[(size_t)c6 * 64 + l];
      float v7 = v[(size_t)c7 * 64 + l];
      acc = fmaf(w0, v0, acc);
      acc = fmaf(w1, v1, acc);
      acc = fmaf(w2, v2, acc);
      acc = fmaf(w3, v3, acc);
      acc = fmaf(w4, v4, acc);
      acc = fmaf(w5, v5, acc);
      acc = fmaf(w6, v6, acc);
      acc = fmaf(w7, v7, acc);
    }
    for (; j + 4 <= m; j += 4) {
      int c0 = __shfl(c, j), c1 = __shfl(c, j + 1), c2 = __shfl(c, j + 2), c3 = __shfl(c, j + 3);
      float w0 = __shfl(w, j), w1 = __shfl(w, j + 1), w2 = __shfl(w, j + 2), w3 = __shfl(w, j + 3);
      float v0 = v[(size_t)c0 * 64 + l];
      float v1 = v[(size_t)c1 * 64 + l];
      float v2 = v[(size_t)c2 * 64 + l];
      float v3 = v[(size_t)c3 * 64 + l];
      acc = fmaf(w0, v0, acc);
      acc = fmaf(w1, v1, acc);
      acc = fmaf(w2, v2, acc);
      acc = fmaf(w3, v3, acc);
    }
    for (; j < m; j++) {
      int cj = __shfl(c, j);
      float wj = __shfl(w, j);
      acc = fmaf(wj, v[(size_t)cj * 64 + l], acc);
    }
  }

  float o = acc / denom;
  float sum = wave_sum(o);
  float sumsq = wave_sum(o * o);
  float var = (sumsq - sum * sum * (1.0f / 64.f)) * (1.0f / 63.f);
  out[(size_t)gw * 64 + l] = o / sqrtf(var);
}

extern "C" void kernel_launch(void* const* d_in, const int* in_sizes, int n_in,
                              void* d_out, int out_size, void* d_ws, size_t ws_size,
                              hipStream_t stream) {
  const float* h = (const float*)d_in[0];
  const int* ei = (const int*)d_in[1];
  const float* W11 = (const float*)d_in[2];
  const float* b11 = (const float*)d_in[3];
  const float* W12 = (const float*)d_in[4];  // [1,64] -> 64-vec
  const float* b12 = (const float*)d_in[5];
  const float* W13 = (const float*)d_in[6];
  const float* b13 = (const float*)d_in[7];
  const float* W21 = (const float*)d_in[8];
  const float* b21 = (const float*)d_in[9];
  const float* W22 = (const float*)d_in[10];
  const float* b22 = (const float*)d_in[11];
  const float* W23 = (const float*)d_in[12];
  const float* b23 = (const float*)d_in[13];

  const int N = in_sizes[0] / 128;  // 100000
  const int E = in_sizes[1] / 2;    // 1600000
  const int* src = ei;
  const int* dst = ei + E;

  // workspace carve-up
  char* p = (char*)d_ws;
  auto alloc = [&](size_t bytes) -> void* {
    void* r = (void*)p;
    p += (bytes + WS_ALIGN - 1) / WS_ALIGN * WS_ALIGN;
    return r;
  };
  int* deg = (int*)alloc((size_t)N * 4);
  int* pre = (int*)alloc((size_t)N * 4);
  int* bsum = (int*)alloc(512);
  int* rowptr = (int*)alloc((size_t)(N + 1) * 4);
  int* cursor = (int*)alloc((size_t)N * 4);
  int* col = (int*)alloc((size_t)E * 4);
  float* sbuf = (float*)alloc((size_t)N * 4);
  float* vbuf = (float*)alloc((size_t)N * 64 * 4);
  float* out1 = (float*)alloc((size_t)N * 64 * 4);

  const int SB = (N + 1023) / 1024;  // 98 (must be <= 128 for k_scan_top)

  // ---- CSR build (reused by both layers) ----
  k_zero<<<(N + 255) / 256, 256, 0, stream>>>(deg, N);
  k_deg<<<(E + 255) / 256, 256, 0, stream>>>(src, deg, E);
  k_scan_part<<<SB, 256, 0, stream>>>(deg, pre, bsum, N);
  k_scan_top<<<1, 128, 0, stream>>>(bsum, SB);
  k_scan_add<<<SB, 256, 0, stream>>>(pre, bsum, rowptr, cursor, N, E);
  k_scatter<<<(E + 255) / 256, 256, 0, stream>>>(src, dst, cursor, col, E);

  // ---- layer 1 (K=128) ----
  k_node<128><<<(N + 31) / 32, 256, 0, stream>>>(h, W11, b11, W12, W13, b13, vbuf, sbuf, N);
  k_aggr<<<(N + 3) / 4, 256, 0, stream>>>(rowptr, col, sbuf, b12, vbuf, out1, N);

  // ---- layer 2 (K=64) ----
  k_node<64><<<(N + 31) / 32, 256, 0, stream>>>(out1, W21, b21, W22, W23, b23, vbuf, sbuf, N);
  k_aggr<<<(N + 3) / 4, 256, 0, stream>>>(rowptr, col, sbuf, b22, vbuf, (float*)d_out, N);
}